// Round 6
// baseline (226.966 us; speedup 1.0000x reference)
//
#include <hip/hip_runtime.h>

#ifndef __has_builtin
#define __has_builtin(x) 0
#endif

__device__ __forceinline__ float fexp2(float v) {
#if __has_builtin(__builtin_amdgcn_exp2f)
    return __builtin_amdgcn_exp2f(v);   // raw v_exp_f32
#else
    return exp2f(v);
#endif
}
__device__ __forceinline__ float frcp(float v) {
#if __has_builtin(__builtin_amdgcn_rcpf)
    return __builtin_amdgcn_rcpf(v);    // raw v_rcp_f32 (~1 ulp; threshold 1.5e-2)
#else
    return 1.0f / v;
#endif
}

// Problem constants: B, CIN, H, W = 8, 1, 192, 192; COUT, KH, KW = 8, 7, 7
constexpr int B_    = 8;
constexpr int H_    = 192;
constexpr int W_    = 192;
constexpr int COUT_ = 8;
constexpr int KH_   = 7;
constexpr int KW_   = 7;
constexpr int HO_   = H_ - KH_ + 1;  // 186
constexpr int WO_   = W_ - KW_ + 1;  // 186
constexpr float LOG2E = 1.44269504088896340736f;

// CHANGE vs R0-R5 (all LDS-staged): every staged variant pinned at main
// ~40 us regardless of tile shape or occupancy (R3: Occ 18%, VALUBusy 26%,
// LDS busy ~7%, HBM 3% -- nothing saturated; R5's forced 8 waves/SIMD
// changed nothing vs R1). The two-phase stage->barrier->read structure IS
// the cost. exp is 1 trans-pipe op; recomputing it per tap is far cheaper
// than the LDS round-trip + barrier. This version: NO LDS, NO barrier.
// Each thread: 4 outputs in x from a 7x10 register window. Per row:
// 10-float load (16B-aligned), 10 exp2 + 10 mul, 84 FMA vs SGPR F/G table.
// 8 indep acc chains, 21 indep loads/thread. Valid conv => interior needs
// no clamping at all; only the last 2 output columns need a tail guard.
constexpr int XS_  = 8;              // x-slots per block (4 outputs each)
constexpr int YR_  = 16;             // output rows per block
constexpr int TX   = 4 * XS_;        // 32 output cols per block
constexpr int TY   = YR_;            // 16 output rows per block

// ws table: per (c,ky) one 16-float row: [F0..F6, 0, G0..G6, 0]
// F = exp(a*f) (as exp2 of a*log2e*f), G = F*f. One s_load_dwordx16 per row.
__global__ void smorph_setup(const float* __restrict__ filt,
                             const float* __restrict__ alpha,
                             float* __restrict__ ws) {
    int i = threadIdx.x;                 // 64 threads, 56 active
    if (i < COUT_ * KH_) {
        int c = i / 7, ky = i - c * 7;
        float a2 = alpha[c] * LOG2E;
        float* t = ws + (c * 7 + ky) * 16;
#pragma unroll
        for (int kx = 0; kx < 7; ++kx) {
            float f = filt[(c * 7 + ky) * 7 + kx];
            float F = fexp2(a2 * f);
            t[kx]     = F;
            t[8 + kx] = F * f;
        }
        t[7] = 0.f; t[15] = 0.f;
    }
}

// exp(a(x+f)) = P * F_k with P = exp2(a2*x).  H = x*P.
// num = sum_k (F_k*H + G_k*P); den = sum_k F_k*P; out = num/den.
__global__ __launch_bounds__(128, 8) void smorph_main(
    const float* __restrict__ x,      // (B,1,H,W)
    const float* __restrict__ alpha,  // (COUT,1)
    const float* __restrict__ fg,     // setup table
    float* __restrict__ out)          // (B,COUT,HO,WO)
{
    const int tid = threadIdx.x;      // 0..127
    const int xs  = tid & (XS_ - 1);
    const int yr  = tid >> 3;         // 0..15
    const int ox0 = blockIdx.x * TX + 4 * xs;   // multiple of 4 -> 16B aligned
    const int oy  = blockIdx.y * TY + yr;
    if (oy >= HO_ || ox0 + 1 >= WO_) return;    // no barrier: early-exit is safe

    const int z = blockIdx.z;         // b*COUT + c
    const int c = z & 7;
    const float* xb = x + (z >> 3) * (H_ * W_);
    const float a2  = alpha[c] * LOG2E;         // uniform -> s_load
    const float* tc = fg + c * (7 * 16);

    // Tail guards (only the last x-slot of the last x-block diverges):
    const bool haveC  = (ox0 + 9) < W_;    // cols ox0+8, ox0+9 exist
    const bool haveHi = (ox0 + 3) < WO_;   // outputs ox0+2, ox0+3 valid

    float num[4] = {0.f, 0.f, 0.f, 0.f};
    float den[4] = {0.f, 0.f, 0.f, 0.f};

#pragma unroll
    for (int ky = 0; ky < KH_; ++ky) {
        const float* t = tc + ky * 16;              // uniform -> s_load_dwordx16
        const float* rb = xb + (oy + ky) * W_ + ox0;
        const float4 a4 = *(const float4*)rb;        // 16B aligned
        const float4 b4 = *(const float4*)(rb + 4);  // 16B aligned
        const float2 c2 = haveC ? *(const float2*)(rb + 8) : make_float2(0.f, 0.f);
        const float xr[10] = {a4.x, a4.y, a4.z, a4.w,
                              b4.x, b4.y, b4.z, b4.w,
                              c2.x, c2.y};
        float P[10], Hh[10];
#pragma unroll
        for (int j = 0; j < 10; ++j) {
            P[j]  = fexp2(a2 * xr[j]);
            Hh[j] = xr[j] * P[j];
        }
#pragma unroll
        for (int kx = 0; kx < KW_; ++kx) {
            const float F = t[kx], G = t[8 + kx];   // SGPR operands
#pragma unroll
            for (int o = 0; o < 4; ++o) {           // all indices static
                num[o] = fmaf(F, Hh[kx + o], num[o]);
                num[o] = fmaf(G, P[kx + o],  num[o]);
                den[o] = fmaf(F, P[kx + o],  den[o]);
            }
        }
    }

    float* ob = out + (size_t)(z * HO_ + oy) * WO_ + ox0;  // 8B aligned
    *(float2*)ob = make_float2(num[0] * frcp(den[0]), num[1] * frcp(den[1]));
    if (haveHi)
        *(float2*)(ob + 2) = make_float2(num[2] * frcp(den[2]), num[3] * frcp(den[3]));
}

extern "C" void kernel_launch(void* const* d_in, const int* in_sizes, int n_in,
                              void* d_out, int out_size, void* d_ws, size_t ws_size,
                              hipStream_t stream) {
    const float* x     = (const float*)d_in[0];
    const float* filt  = (const float*)d_in[1];
    const float* alpha = (const float*)d_in[2];
    float* out = (float*)d_out;
    float* ws  = (float*)d_ws;

    smorph_setup<<<1, 64, 0, stream>>>(filt, alpha, ws);

    dim3 block(128, 1, 1);
    dim3 grid((WO_ + TX - 1) / TX, (HO_ + TY - 1) / TY, B_ * COUT_);  // (6, 12, 64)
    smorph_main<<<grid, block, 0, stream>>>(x, alpha, ws, out);
}

// Round 7
// 109.496 us; speedup vs baseline: 2.0728x; 2.0728x over previous
//
#include <hip/hip_runtime.h>

#ifndef __has_builtin
#define __has_builtin(x) 0
#endif

__device__ __forceinline__ float fexp2(float v) {
#if __has_builtin(__builtin_amdgcn_exp2f)
    return __builtin_amdgcn_exp2f(v);   // raw v_exp_f32
#else
    return exp2f(v);
#endif
}
__device__ __forceinline__ float frcp(float v) {
#if __has_builtin(__builtin_amdgcn_rcpf)
    return __builtin_amdgcn_rcpf(v);    // raw v_rcp_f32 (~1 ulp; threshold 1.5e-2)
#else
    return 1.0f / v;
#endif
}

// Problem constants: B, CIN, H, W = 8, 1, 192, 192; COUT, KH, KW = 8, 7, 7
constexpr int B_    = 8;
constexpr int H_    = 192;
constexpr int W_    = 192;
constexpr int COUT_ = 8;
constexpr int KH_   = 7;
constexpr int KW_   = 7;
constexpr int HO_   = H_ - KH_ + 1;  // 186
constexpr int WO_   = W_ - KW_ + 1;  // 186
constexpr float LOG2E = 1.44269504088896340736f;

// R6 post-mortem: __launch_bounds__(128,8) forced VGPR=32 < ~55 live
// values -> full spill to scratch (WRITE_SIZE 352 MB vs 8.9 MB output,
// FETCH 176 MB, VALUBusy 8%, main 175 us). The no-LDS structure was never
// actually measured. R7 = identical kernel, launch_bounds relaxed to
// (128,4): VGPR cap 128, expect ~64-96 natural allocation, zero spills.
constexpr int XS_  = 8;              // x-slots per block (4 outputs each)
constexpr int YR_  = 16;             // output rows per block
constexpr int TX   = 4 * XS_;        // 32 output cols per block
constexpr int TY   = YR_;            // 16 output rows per block

// ws table: per (c,ky) one 16-float row: [F0..F6, 0, G0..G6, 0]
// F = exp(a*f) (as exp2 of a*log2e*f), G = F*f. One s_load_dwordx16 per row.
__global__ void smorph_setup(const float* __restrict__ filt,
                             const float* __restrict__ alpha,
                             float* __restrict__ ws) {
    int i = threadIdx.x;                 // 64 threads, 56 active
    if (i < COUT_ * KH_) {
        int c = i / 7, ky = i - c * 7;
        float a2 = alpha[c] * LOG2E;
        float* t = ws + (c * 7 + ky) * 16;
#pragma unroll
        for (int kx = 0; kx < 7; ++kx) {
            float f = filt[(c * 7 + ky) * 7 + kx];
            float F = fexp2(a2 * f);
            t[kx]     = F;
            t[8 + kx] = F * f;
        }
        t[7] = 0.f; t[15] = 0.f;
    }
}

// exp(a(x+f)) = P * F_k with P = exp2(a2*x).  H = x*P.
// num = sum_k (F_k*H + G_k*P); den = sum_k F_k*P; out = num/den.
// No LDS, no barrier. Each thread: 4 outputs in x from a 7x10 register
// window. Per row: 10-float load (16B-aligned), 10 exp2 + 10 mul, then
// 84 FMA against the SGPR-resident F/G table row. 8 indep acc chains.
__global__ __launch_bounds__(128, 4) void smorph_main(
    const float* __restrict__ x,      // (B,1,H,W)
    const float* __restrict__ alpha,  // (COUT,1)
    const float* __restrict__ fg,     // setup table
    float* __restrict__ out)          // (B,COUT,HO,WO)
{
    const int tid = threadIdx.x;      // 0..127
    const int xs  = tid & (XS_ - 1);
    const int yr  = tid >> 3;         // 0..15
    const int ox0 = blockIdx.x * TX + 4 * xs;   // multiple of 4 -> 16B aligned
    const int oy  = blockIdx.y * TY + yr;
    if (oy >= HO_ || ox0 + 1 >= WO_) return;    // no barrier: early-exit is safe

    const int z = blockIdx.z;         // b*COUT + c
    const int c = z & 7;
    const float* xb = x + (z >> 3) * (H_ * W_);
    const float a2  = alpha[c] * LOG2E;         // uniform -> s_load
    const float* tc = fg + c * (7 * 16);

    // Tail guards (only the last x-slot of the last x-block diverges):
    const bool haveC  = (ox0 + 9) < W_;    // cols ox0+8, ox0+9 exist
    const bool haveHi = (ox0 + 3) < WO_;   // outputs ox0+2, ox0+3 valid

    float num[4] = {0.f, 0.f, 0.f, 0.f};
    float den[4] = {0.f, 0.f, 0.f, 0.f};

#pragma unroll
    for (int ky = 0; ky < KH_; ++ky) {
        const float* t = tc + ky * 16;              // uniform -> s_load_dwordx16
        const float* rb = xb + (oy + ky) * W_ + ox0;
        const float4 a4 = *(const float4*)rb;        // 16B aligned
        const float4 b4 = *(const float4*)(rb + 4);  // 16B aligned
        const float2 c2 = haveC ? *(const float2*)(rb + 8) : make_float2(0.f, 0.f);
        const float xr[10] = {a4.x, a4.y, a4.z, a4.w,
                              b4.x, b4.y, b4.z, b4.w,
                              c2.x, c2.y};
        float P[10], Hh[10];
#pragma unroll
        for (int j = 0; j < 10; ++j) {
            P[j]  = fexp2(a2 * xr[j]);
            Hh[j] = xr[j] * P[j];
        }
#pragma unroll
        for (int kx = 0; kx < KW_; ++kx) {
            const float F = t[kx], G = t[8 + kx];   // SGPR operands
#pragma unroll
            for (int o = 0; o < 4; ++o) {           // all indices static
                num[o] = fmaf(F, Hh[kx + o], num[o]);
                num[o] = fmaf(G, P[kx + o],  num[o]);
                den[o] = fmaf(F, P[kx + o],  den[o]);
            }
        }
    }

    float* ob = out + (size_t)(z * HO_ + oy) * WO_ + ox0;  // 8B aligned
    *(float2*)ob = make_float2(num[0] * frcp(den[0]), num[1] * frcp(den[1]));
    if (haveHi)
        *(float2*)(ob + 2) = make_float2(num[2] * frcp(den[2]), num[3] * frcp(den[3]));
}

extern "C" void kernel_launch(void* const* d_in, const int* in_sizes, int n_in,
                              void* d_out, int out_size, void* d_ws, size_t ws_size,
                              hipStream_t stream) {
    const float* x     = (const float*)d_in[0];
    const float* filt  = (const float*)d_in[1];
    const float* alpha = (const float*)d_in[2];
    float* out = (float*)d_out;
    float* ws  = (float*)d_ws;

    smorph_setup<<<1, 64, 0, stream>>>(filt, alpha, ws);

    dim3 block(128, 1, 1);
    dim3 grid((WO_ + TX - 1) / TX, (HO_ + TY - 1) / TY, B_ * COUT_);  // (6, 12, 64)
    smorph_main<<<grid, block, 0, stream>>>(x, alpha, ws, out);
}

// Round 8
// 85.801 us; speedup vs baseline: 2.6453x; 1.2762x over previous
//
#include <hip/hip_runtime.h>

#ifndef __has_builtin
#define __has_builtin(x) 0
#endif

__device__ __forceinline__ float fexp2(float v) {
#if __has_builtin(__builtin_amdgcn_exp2f)
    return __builtin_amdgcn_exp2f(v);   // raw v_exp_f32
#else
    return exp2f(v);
#endif
}
__device__ __forceinline__ float frcp(float v) {
#if __has_builtin(__builtin_amdgcn_rcpf)
    return __builtin_amdgcn_rcpf(v);    // raw v_rcp_f32 (~1 ulp; threshold 1.5e-2)
#else
    return 1.0f / v;
#endif
}

// Problem constants: B, CIN, H, W = 8, 1, 192, 192; COUT, KH, KW = 8, 7, 7
constexpr int B_    = 8;
constexpr int H_    = 192;
constexpr int W_    = 192;
constexpr int COUT_ = 8;
constexpr int KH_   = 7;
constexpr int KW_   = 7;
constexpr int HO_   = H_ - KH_ + 1;  // 186
constexpr int WO_   = W_ - KW_ + 1;  // 186
constexpr float LOG2E = 1.44269504088896340736f;

// R7 post-mortem: VGPR=64 still spilled (~108 MB scratch writes/dispatch,
// WRITE 117 MB vs 8.9 MB output, VALUBusy 22%, main 54.5 us). Live set
// (xr[10]+P[10]+Hh[10]+8acc+hoisted loads) exceeds 64. R8 fixes both
// sides: (a) algebra: F*H+G*P = P*(F*x+G) -> Hh[] never exists (-10 regs,
// same 3 FMA/tap); (b) __launch_bounds__(128) with NO min-wave arg ->
// allocator free to take ~80-112 VGPR, spill-free, instead of clamping.
constexpr int XS_  = 8;              // x-slots per block (4 outputs each)
constexpr int YR_  = 16;             // output rows per block
constexpr int TX   = 4 * XS_;        // 32 output cols per block
constexpr int TY   = YR_;            // 16 output rows per block

// ws table: per (c,ky) one 16-float row: [F0..F6, 0, G0..G6, 0]
// F = exp(a*f) (as exp2 of a*log2e*f), G = F*f. One s_load_dwordx16 per row.
__global__ void smorph_setup(const float* __restrict__ filt,
                             const float* __restrict__ alpha,
                             float* __restrict__ ws) {
    int i = threadIdx.x;                 // 64 threads, 56 active
    if (i < COUT_ * KH_) {
        int c = i / 7, ky = i - c * 7;
        float a2 = alpha[c] * LOG2E;
        float* t = ws + (c * 7 + ky) * 16;
#pragma unroll
        for (int kx = 0; kx < 7; ++kx) {
            float f = filt[(c * 7 + ky) * 7 + kx];
            float F = fexp2(a2 * f);
            t[kx]     = F;
            t[8 + kx] = F * f;
        }
        t[7] = 0.f; t[15] = 0.f;
    }
}

// exp(a(x+f)) = P * F_k with P = exp2(a2*x).
// num = sum_k (F_k*x + G_k) * P;  den = sum_k F_k * P;  out = num/den.
// No LDS, no barrier. Each thread: 4 outputs in x from a 7x10 register
// window. Per row: 10-float load (16B-aligned), 10 exp2, then 84 FMA
// against the SGPR-resident F/G table row. 8 indep acc chains.
__global__ __launch_bounds__(128) void smorph_main(
    const float* __restrict__ x,      // (B,1,H,W)
    const float* __restrict__ alpha,  // (COUT,1)
    const float* __restrict__ fg,     // setup table
    float* __restrict__ out)          // (B,COUT,HO,WO)
{
    const int tid = threadIdx.x;      // 0..127
    const int xs  = tid & (XS_ - 1);
    const int yr  = tid >> 3;         // 0..15
    const int ox0 = blockIdx.x * TX + 4 * xs;   // multiple of 4 -> 16B aligned
    const int oy  = blockIdx.y * TY + yr;
    if (oy >= HO_ || ox0 + 1 >= WO_) return;    // no barrier: early-exit is safe

    const int z = blockIdx.z;         // b*COUT + c
    const int c = z & 7;
    const float* xb = x + (z >> 3) * (H_ * W_);
    const float a2  = alpha[c] * LOG2E;         // uniform -> s_load
    const float* tc = fg + c * (7 * 16);

    // Tail guards (only the last x-slot of the last x-block diverges):
    const bool haveC  = (ox0 + 9) < W_;    // cols ox0+8, ox0+9 exist
    const bool haveHi = (ox0 + 3) < WO_;   // outputs ox0+2, ox0+3 valid

    float num[4] = {0.f, 0.f, 0.f, 0.f};
    float den[4] = {0.f, 0.f, 0.f, 0.f};

#pragma unroll
    for (int ky = 0; ky < KH_; ++ky) {
        const float* t = tc + ky * 16;              // uniform -> s_load_dwordx16
        const float* rb = xb + (oy + ky) * W_ + ox0;
        const float4 a4 = *(const float4*)rb;        // 16B aligned
        const float4 b4 = *(const float4*)(rb + 4);  // 16B aligned
        const float2 c2 = haveC ? *(const float2*)(rb + 8) : make_float2(0.f, 0.f);
        const float xr[10] = {a4.x, a4.y, a4.z, a4.w,
                              b4.x, b4.y, b4.z, b4.w,
                              c2.x, c2.y};
        float P[10];
#pragma unroll
        for (int j = 0; j < 10; ++j)
            P[j] = fexp2(a2 * xr[j]);
#pragma unroll
        for (int kx = 0; kx < KW_; ++kx) {
            const float F = t[kx], G = t[8 + kx];   // SGPR operands
#pragma unroll
            for (int o = 0; o < 4; ++o) {           // all indices static
                const float s = fmaf(F, xr[kx + o], G);   // F*x + G
                num[o] = fmaf(s, P[kx + o], num[o]);
                den[o] = fmaf(F, P[kx + o], den[o]);
            }
        }
    }

    float* ob = out + (size_t)(z * HO_ + oy) * WO_ + ox0;  // 8B aligned
    *(float2*)ob = make_float2(num[0] * frcp(den[0]), num[1] * frcp(den[1]));
    if (haveHi)
        *(float2*)(ob + 2) = make_float2(num[2] * frcp(den[2]), num[3] * frcp(den[3]));
}

extern "C" void kernel_launch(void* const* d_in, const int* in_sizes, int n_in,
                              void* d_out, int out_size, void* d_ws, size_t ws_size,
                              hipStream_t stream) {
    const float* x     = (const float*)d_in[0];
    const float* filt  = (const float*)d_in[1];
    const float* alpha = (const float*)d_in[2];
    float* out = (float*)d_out;
    float* ws  = (float*)d_ws;

    smorph_setup<<<1, 64, 0, stream>>>(filt, alpha, ws);

    dim3 block(128, 1, 1);
    dim3 grid((WO_ + TX - 1) / TX, (HO_ + TY - 1) / TY, B_ * COUT_);  // (6, 12, 64)
    smorph_main<<<grid, block, 0, stream>>>(x, alpha, ws, out);
}

// Round 9
// 82.865 us; speedup vs baseline: 2.7390x; 1.0354x over previous
//
#include <hip/hip_runtime.h>

#ifndef __has_builtin
#define __has_builtin(x) 0
#endif

__device__ __forceinline__ float fexp2(float v) {
#if __has_builtin(__builtin_amdgcn_exp2f)
    return __builtin_amdgcn_exp2f(v);   // raw v_exp_f32
#else
    return exp2f(v);
#endif
}
__device__ __forceinline__ float frcp(float v) {
#if __has_builtin(__builtin_amdgcn_rcpf)
    return __builtin_amdgcn_rcpf(v);    // raw v_rcp_f32 (~1 ulp; threshold 1.5e-2)
#else
    return 1.0f / v;
#endif
}

// Problem constants: B, CIN, H, W = 8, 1, 192, 192; COUT, KH, KW = 8, 7, 7
constexpr int B_    = 8;
constexpr int H_    = 192;
constexpr int W_    = 192;
constexpr int COUT_ = 8;
constexpr int KH_   = 7;
constexpr int KW_   = 7;
constexpr int HO_   = H_ - KH_ + 1;  // 186
constexpr int WO_   = W_ - KW_ + 1;  // 186
constexpr float LOG2E = 1.44269504088896340736f;

// R8 post-mortem: main dropped below the 40.5us fill (better than R7's
// 54.5) but counters for main were absent; spill elimination unconfirmed
// and dur suggests main ~40: likely PARTIAL spills remain (unrolled ky
// loop hoists loads, inflating pressure past the allocator's pick).
// R9: make spills IMPOSSIBLE -- 2 outputs/thread, per-row window is
// exactly 8 floats. Live set: xr[8]+P[8]+4acc+addr ~= 30 regs. Loads are
// 4x float2/row (ox0 even -> 8B aligned), 28 independent loads/thread.
// All loads statically in-bounds (max col/row = 191 < 192): no clamps.
// Grid (6,24,64) = 9216 blocks x 128thr = 17 waves/SIMD of work.
constexpr int NTHR = 128;
constexpr int XS_  = 16;             // x-slots per block (2 outputs each)
constexpr int TX   = 2 * XS_;        // 32 output cols per block
constexpr int TY   = 8;              // output rows per block

// ws table: per (c,ky) one 16-float row: [F0..F6, 0, G0..G6, 0]
// F = exp(a*f) (as exp2 of a*log2e*f), G = F*f. One s_load_dwordx16 per row.
__global__ void smorph_setup(const float* __restrict__ filt,
                             const float* __restrict__ alpha,
                             float* __restrict__ ws) {
    int i = threadIdx.x;                 // 64 threads, 56 active
    if (i < COUT_ * KH_) {
        int c = i / 7, ky = i - c * 7;
        float a2 = alpha[c] * LOG2E;
        float* t = ws + (c * 7 + ky) * 16;
#pragma unroll
        for (int kx = 0; kx < 7; ++kx) {
            float f = filt[(c * 7 + ky) * 7 + kx];
            float F = fexp2(a2 * f);
            t[kx]     = F;
            t[8 + kx] = F * f;
        }
        t[7] = 0.f; t[15] = 0.f;
    }
}

// exp(a(x+f)) = P * F_k with P = exp2(a2*x).
// num = sum_k (F_k*x + G_k) * P;  den = sum_k F_k * P;  out = num/den.
// No LDS, no barrier, no clamping. Each thread: 2 outputs in x from a
// 7x8 register window. Per row: 4x float2 load, 8 exp2, 42 FMA against
// the SGPR-resident F/G table row. 4 indep acc chains.
__global__ __launch_bounds__(NTHR) void smorph_main(
    const float* __restrict__ x,      // (B,1,H,W)
    const float* __restrict__ alpha,  // (COUT,1)
    const float* __restrict__ fg,     // setup table
    float* __restrict__ out)          // (B,COUT,HO,WO)
{
    const int tid = threadIdx.x;      // 0..127
    const int xs  = tid & (XS_ - 1);  // 0..15
    const int yr  = tid >> 4;         // 0..7
    const int ox0 = blockIdx.x * TX + 2 * xs;   // even -> 8B aligned
    const int oy  = blockIdx.y * TY + yr;
    if (oy >= HO_ || ox0 + 1 >= WO_) return;    // no barrier: early-exit safe
    // Loads below touch cols ox0..ox0+7 (max 184+7=191 < 192) and rows
    // oy..oy+6 (max 185+6=191 < 192): statically in-bounds.

    const int z = blockIdx.z;         // b*COUT + c
    const int c = z & 7;
    const float* xb = x + (z >> 3) * (H_ * W_);
    const float a2  = alpha[c] * LOG2E;         // uniform -> s_load
    const float* tc = fg + c * (7 * 16);

    float num0 = 0.f, den0 = 0.f, num1 = 0.f, den1 = 0.f;

#pragma unroll
    for (int ky = 0; ky < KH_; ++ky) {
        const float* t = tc + ky * 16;              // uniform -> s_load_dwordx16
        const float* rb = xb + (oy + ky) * W_ + ox0;
        const float2 q0 = *(const float2*)(rb);
        const float2 q1 = *(const float2*)(rb + 2);
        const float2 q2 = *(const float2*)(rb + 4);
        const float2 q3 = *(const float2*)(rb + 6);
        const float xr[8] = {q0.x, q0.y, q1.x, q1.y, q2.x, q2.y, q3.x, q3.y};
        float P[8];
#pragma unroll
        for (int j = 0; j < 8; ++j)
            P[j] = fexp2(a2 * xr[j]);
#pragma unroll
        for (int kx = 0; kx < KW_; ++kx) {
            const float F = t[kx], G = t[8 + kx];   // SGPR operands
            const float s0 = fmaf(F, xr[kx],     G);   // F*x + G
            const float s1 = fmaf(F, xr[kx + 1], G);
            num0 = fmaf(s0, P[kx],     num0);
            den0 = fmaf(F,  P[kx],     den0);
            num1 = fmaf(s1, P[kx + 1], num1);
            den1 = fmaf(F,  P[kx + 1], den1);
        }
    }

    float* ob = out + (size_t)(z * HO_ + oy) * WO_ + ox0;  // 8B aligned
    *(float2*)ob = make_float2(num0 * frcp(den0), num1 * frcp(den1));
}

extern "C" void kernel_launch(void* const* d_in, const int* in_sizes, int n_in,
                              void* d_out, int out_size, void* d_ws, size_t ws_size,
                              hipStream_t stream) {
    const float* x     = (const float*)d_in[0];
    const float* filt  = (const float*)d_in[1];
    const float* alpha = (const float*)d_in[2];
    float* out = (float*)d_out;
    float* ws  = (float*)d_ws;

    smorph_setup<<<1, 64, 0, stream>>>(filt, alpha, ws);

    dim3 block(NTHR, 1, 1);
    dim3 grid((WO_ + TX - 1) / TX, (HO_ + TY - 1) / TY, B_ * COUT_);  // (6, 24, 64)
    smorph_main<<<grid, block, 0, stream>>>(x, alpha, ws, out);
}

// Round 10
// 75.371 us; speedup vs baseline: 3.0113x; 1.0994x over previous
//
#include <hip/hip_runtime.h>

#ifndef __has_builtin
#define __has_builtin(x) 0
#endif

__device__ __forceinline__ float fexp2(float v) {
#if __has_builtin(__builtin_amdgcn_exp2f)
    return __builtin_amdgcn_exp2f(v);   // raw v_exp_f32
#else
    return exp2f(v);
#endif
}
__device__ __forceinline__ float frcp(float v) {
#if __has_builtin(__builtin_amdgcn_rcpf)
    return __builtin_amdgcn_rcpf(v);    // raw v_rcp_f32 (~1 ulp; threshold 1.5e-2)
#else
    return 1.0f / v;
#endif
}

// Problem constants: B, CIN, H, W = 8, 1, 192, 192; COUT, KH, KW = 8, 7, 7
constexpr int B_    = 8;
constexpr int H_    = 192;
constexpr int W_    = 192;
constexpr int COUT_ = 8;
constexpr int KH_   = 7;
constexpr int KW_   = 7;
constexpr int HO_   = H_ - KH_ + 1;  // 186
constexpr int WO_   = W_ - KW_ + 1;  // 186
constexpr float LOG2E = 1.44269504088896340736f;

// R9 post-mortem: clean no-LDS recompute main ~= 40 us -- worse than the
// staged R1 (~31). Recompute trades 28 ds_reads for 28 global loads PLUS
// 112 extra VALU/trans ops (56 redundant exps). Staged structure wins.
// R10 = R1 verbatim EXCEPT two structural overheads removed:
//  (1) setup kernel folded into main: each block computes its channel's
//      7x16 F/G table into LDS during phase 1 (112 threads x 1 exp),
//      sharing the existing barrier. One launch instead of two.
//  (2) K-loop table operands come from LDS instead of s_load_dwordx16:
//      s_load shares lgkmcnt with ds_read and 112 SGPRs can't be hoisted,
//      so per-ky scalar-cache waits (~200 cyc) serialized the loop.
//      Uniform-address ds_read_b128 broadcasts are prefetchable and
//      conflict-free; F/G become uniform VGPRs (fine for VOP3 FMA).
constexpr int TX   = 64;             // output tile x per block
constexpr int TY   = 8;              // output tile y per block
constexpr int IX   = TX + KW_ - 1;   // 70 input cols staged
constexpr int IY   = TY + KH_ - 1;   // 14 input rows staged
constexpr int NPIX = IX * IY;        // 980

// exp(a(x+f)) = P * F_k with P = exp2(a2*x).  H = x*P.
// num = sum_k (F_k*H + G_k*P); den = sum_k F_k*P; out = num/den.
__global__ __launch_bounds__(256) void smorph_main(
    const float* __restrict__ x,      // (B,1,H,W)
    const float* __restrict__ filt,   // (COUT,1,7,7)
    const float* __restrict__ alpha,  // (COUT,1)
    float* __restrict__ out)          // (B,COUT,HO,WO)
{
    __shared__ __align__(16) float2 PH[IY * IX];   // 7840 B
    __shared__ __align__(16) float  TAB[KH_ * 16]; // 448 B: per ky [F0..F6,0,G0..G6,0]

    const int tx  = threadIdx.x;      // 0..31
    const int ty  = threadIdx.y;      // 0..7
    const int tid = ty * 32 + tx;
    const int bx0 = blockIdx.x * TX;
    const int by0 = blockIdx.y * TY;
    const int z   = blockIdx.z;       // b*COUT + c
    const int c   = z & 7;
    const float* xb = x + (z >> 3) * (H_ * W_);
    const float a2  = alpha[c] * LOG2E;   // uniform -> s_load

    // Phase 1a: F/G table for this block's channel (112 threads, 1 exp each).
    if (tid < KH_ * 16) {
        const int ky = tid >> 4, j = tid & 15;
        float v = 0.f;                     // pads j==7, j==15
        if (j < 7) {
            const float f = filt[(c * 7 + ky) * 7 + j];
            v = fexp2(a2 * f);                       // F
        } else if (j < 15) {
            const float f = filt[(c * 7 + ky) * 7 + (j - 8)];
            v = fexp2(a2 * f) * f;                   // G = F*f
        }
        TAB[tid] = v;
    }

    // Phase 1b: stage P,H (4 slots/thread; slot 3: 212 threads active).
    const int i0 = tid, i1 = tid + 256, i2 = tid + 512, i3 = tid + 768;
    const int iy0 = i0 / IX, ix0 = i0 - iy0 * IX;
    const int iy1 = i1 / IX, ix1 = i1 - iy1 * IX;
    const int iy2 = i2 / IX, ix2 = i2 - iy2 * IX;
    const int iy3 = i3 / IX, ix3 = i3 - iy3 * IX;
    const bool has3 = (i3 < NPIX);

    // Clamped coords only feed masked outputs.
    const float xv0 = xb[min(by0 + iy0, H_ - 1) * W_ + min(bx0 + ix0, W_ - 1)];
    const float xv1 = xb[min(by0 + iy1, H_ - 1) * W_ + min(bx0 + ix1, W_ - 1)];
    const float xv2 = xb[min(by0 + iy2, H_ - 1) * W_ + min(bx0 + ix2, W_ - 1)];
    const float xv3 = has3 ? xb[min(by0 + iy3, H_ - 1) * W_ + min(bx0 + ix3, W_ - 1)] : 0.f;
    {
        float P;
        P = fexp2(a2 * xv0); PH[i0] = make_float2(P, xv0 * P);
        P = fexp2(a2 * xv1); PH[i1] = make_float2(P, xv1 * P);
        P = fexp2(a2 * xv2); PH[i2] = make_float2(P, xv2 * P);
        if (has3) { P = fexp2(a2 * xv3); PH[i3] = make_float2(P, xv3 * P); }
    }
    __syncthreads();   // the only barrier (covers TAB and PH)

    // Phase 2: 7x7 correlation, 2 outputs/thread.
    const int ox = bx0 + 2 * tx;
    const int oy = by0 + ty;
    const bool valid = (ox + 1 < WO_) && (oy < HO_);  // ox even: both-or-neither

    float num0 = 0.f, den0 = 0.f, num1 = 0.f, den1 = 0.f;
#pragma unroll
    for (int ky = 0; ky < KH_; ++ky) {
        // Uniform-address broadcast reads (conflict-free, prefetchable):
        const float4 F0 = *(const float4*)&TAB[ky * 16];
        const float4 F1 = *(const float4*)&TAB[ky * 16 + 4];
        const float4 G0 = *(const float4*)&TAB[ky * 16 + 8];
        const float4 G1 = *(const float4*)&TAB[ky * 16 + 12];
        const float Ft[7] = {F0.x, F0.y, F0.z, F0.w, F1.x, F1.y, F1.z};
        const float Gt[7] = {G0.x, G0.y, G0.z, G0.w, G1.x, G1.y, G1.z};

        const float4* rp = (const float4*)&PH[(ty + ky) * IX + 2 * tx];
        float4 q0 = rp[0], q1 = rp[1], q2 = rp[2], q3 = rp[3];
        float P[8]  = {q0.x, q0.z, q1.x, q1.z, q2.x, q2.z, q3.x, q3.z};
        float Hh[8] = {q0.y, q0.w, q1.y, q1.w, q2.y, q2.w, q3.y, q3.w};
#pragma unroll
        for (int kx = 0; kx < 7; ++kx) {
            const float F = Ft[kx], G = Gt[kx];
            num0 = fmaf(F, Hh[kx],     num0);
            num0 = fmaf(G, P[kx],      num0);
            den0 = fmaf(F, P[kx],      den0);
            num1 = fmaf(F, Hh[kx + 1], num1);
            num1 = fmaf(G, P[kx + 1],  num1);
            den1 = fmaf(F, P[kx + 1],  den1);
        }
    }

    if (valid) {
        float2 o;
        o.x = num0 * frcp(den0);
        o.y = num1 * frcp(den1);
        *(float2*)&out[((size_t)(z * HO_ + oy)) * WO_ + ox] = o;
    }
}

extern "C" void kernel_launch(void* const* d_in, const int* in_sizes, int n_in,
                              void* d_out, int out_size, void* d_ws, size_t ws_size,
                              hipStream_t stream) {
    const float* x     = (const float*)d_in[0];
    const float* filt  = (const float*)d_in[1];
    const float* alpha = (const float*)d_in[2];
    float* out = (float*)d_out;

    dim3 block(32, 8, 1);
    dim3 grid((WO_ + TX - 1) / TX, (HO_ + TY - 1) / TY, B_ * COUT_);  // (3, 24, 64)
    smorph_main<<<grid, block, 0, stream>>>(x, filt, alpha, out);
}